// Round 8
// baseline (255.463 us; speedup 1.0000x reference)
//
#include <hip/hip_runtime.h>

#define N_NODES 100000
#define N_EDGES 1600000
#define D 128
#define NB 391        // 256-row buckets
#define BCAP 4608     // mean 4096 edges/bucket + 8 sigma
#define BSTRIDE 16    // bucket counter padding (64 B)
#define CHUNK 4000    // edges per scatter block; 400 blocks x 4000 = 1.6M exactly
#define NSCAT 400
#define NGEMM 1563    // ceil(100000/64)

typedef __attribute__((ext_vector_type(8))) short  short8;   // 8 bf16 (4 VGPR) MFMA A/B frag
typedef __attribute__((ext_vector_type(4))) float  floatx4;  // MFMA C/D frag / clang vec for nontemporal

__device__ __forceinline__ ushort f2bf(float f) {   // fp32 -> bf16 RNE
    unsigned u = __float_as_uint(f);
    u += 0x7FFF + ((u >> 16) & 1);
    return (ushort)(u >> 16);
}
__device__ __forceinline__ float bf2f(ushort s) {
    return __uint_as_float((unsigned)s << 16);
}

// ---------------- fused: gemm (blocks 0..NGEMM) + bucket_scatter (blocks NGEMM..NGEMM+NSCAT) ----------------
// Same-stream kernels serialize; fusing overlaps the two independent pipelines.
union SMem {
    struct {                       // scatter branch: 47224 B
        int2  stage[CHUNK];        // 32000
        int   sA[512];             //  2048
        int   sB[512];             //  2048
        int   lcur[NB];            //  1564
        int   gbase[NB];           //  1564
        short sbuck[CHUNK];        //  8000
    } sc;
    ushort wt[128 * 128];          // gemm branch: 32768 B
};

__global__ __launch_bounds__(256) void gemm_and_scatter(const float* __restrict__ x,
                                                        const float* __restrict__ w,
                                                        ushort* __restrict__ xwb,
                                                        const int* __restrict__ erow,
                                                        const int* __restrict__ ecol,
                                                        const float* __restrict__ eval,
                                                        int* __restrict__ bcnt,
                                                        int2* __restrict__ bkt) {
    __shared__ SMem sm;
    const int t = threadIdx.x;

    if (blockIdx.x < NGEMM) {
        // ================= GEMM: xw = bf16(x @ w) via MFMA =================
        // wave computes 16 rows x 128 cols; W transposed bf16 in LDS, XOR-swizzled 16 B chunks.
        ushort* wt = sm.wt;
        const int wv   = t >> 6;
        const int lane = t & 63;
        const int m    = lane & 15;
        const int q    = lane >> 4;

        {
            const float4* w4 = (const float4*)w;   // 4096 float4 = 128x128 fp32
            for (int i = t; i < 4096; i += 256) {
                const float4 v = w4[i];
                const int k = i >> 5;
                const int n = (i & 31) << 2;
                const int c = k >> 3, kc = k & 7;
#pragma unroll
                for (int d = 0; d < 4; ++d) {
                    const float val = (d == 0) ? v.x : (d == 1) ? v.y : (d == 2) ? v.z : v.w;
                    const int nn = n + d;
                    wt[(nn << 7) | (((c ^ (nn & 15)) & 15) << 3) | kc] = f2bf(val);
                }
            }
        }
        __syncthreads();

        const int rbase = blockIdx.x * 64 + wv * 16;
        if (rbase >= N_NODES) return;              // wave-uniform

        const float* xrow = x + (size_t)(rbase + m) * D;

        floatx4 acc[8];
#pragma unroll
        for (int tt = 0; tt < 8; ++tt) acc[tt] = (floatx4){0.f, 0.f, 0.f, 0.f};

#pragma unroll
        for (int kk = 0; kk < D; kk += 32) {
            const float4 a0 = *(const float4*)(xrow + kk + q * 8);
            const float4 a1 = *(const float4*)(xrow + kk + q * 8 + 4);
            short8 a;
            a[0] = (short)f2bf(a0.x); a[1] = (short)f2bf(a0.y);
            a[2] = (short)f2bf(a0.z); a[3] = (short)f2bf(a0.w);
            a[4] = (short)f2bf(a1.x); a[5] = (short)f2bf(a1.y);
            a[6] = (short)f2bf(a1.z); a[7] = (short)f2bf(a1.w);

#pragma unroll
            for (int tt = 0; tt < 8; ++tt) {
                const int n  = tt * 16 + m;
                const int cc = (((kk >> 3) + q) ^ m) & 15;
                const short8 b = *(const short8*)&wt[(n << 7) | (cc << 3)];
                acc[tt] = __builtin_amdgcn_mfma_f32_16x16x32_bf16(a, b, acc[tt], 0, 0, 0);
            }
        }

#pragma unroll
        for (int tt = 0; tt < 8; ++tt) {
#pragma unroll
            for (int r = 0; r < 4; ++r) {
                xwb[(size_t)(rbase + q * 4 + r) * D + tt * 16 + m] = f2bf(acc[tt][r]);
            }
        }
    } else {
        // ================= bucket_scatter: LDS counting-sort by bucket =================
        const int e0 = (blockIdx.x - NGEMM) * CHUNK;
        int*   sA    = sm.sc.sA;
        int*   sB    = sm.sc.sB;
        int*   lcur  = sm.sc.lcur;
        int*   gbase = sm.sc.gbase;
        short* sbuck = sm.sc.sbuck;
        int2*  stage = sm.sc.stage;

        sA[t] = 0; sA[t + 256] = 0;
        __syncthreads();

        // pass A: histogram by bucket
        for (int i = t; i < CHUNK; i += 256) {
            atomicAdd(&sA[erow[e0 + i] >> 8], 1);
        }
        __syncthreads();

        // inclusive Hillis-Steele scan over 512 slots (2/thread)
        int cur = 0;
        int* bufs[2] = {sA, sB};
#pragma unroll
        for (int o = 1; o < 512; o <<= 1) {
            const int* src = bufs[cur];
            int*       dst = bufs[cur ^ 1];
            const int i0 = t, i1 = t + 256;
            dst[i0] = src[i0] + ((i0 >= o) ? src[i0 - o] : 0);
            dst[i1] = src[i1] + ((i1 >= o) ? src[i1 - o] : 0);
            cur ^= 1;
            __syncthreads();
        }
        {
            const int* incl = bufs[cur];
            int*       excl = bufs[cur ^ 1];
            excl[t]       = (t == 0) ? 0 : incl[t - 1];
            excl[t + 256] = incl[t + 255];
        }
        __syncthreads();
        int* L = bufs[cur ^ 1];

        for (int b = t; b < NB; b += 256) {
            lcur[b] = L[b];
            const int cnt = L[b + 1] - L[b];
            gbase[b] = (cnt > 0) ? atomicAdd(&bcnt[b * BSTRIDE], cnt) : 0;
        }
        __syncthreads();

        // pass B: place into LDS sorted by bucket; record bucket id per slot
        for (int i = t; i < CHUNK; i += 256) {
            const int   r = erow[e0 + i];
            const int   c = ecol[e0 + i];
            const float v = eval[e0 + i];
            const int   b = r >> 8;
            const int pos = atomicAdd(&lcur[b], 1);
            stage[pos] = make_int2(((r & 255) << 17) | c, __float_as_int(v));
            sbuck[pos] = (short)b;
        }
        __syncthreads();

        // flush: consecutive threads -> consecutive addresses within each run
        for (int i = t; i < CHUNK; i += 256) {
            const int b   = sbuck[i];
            const int dst = gbase[b] + (i - L[b]);
            if (dst < BCAP) bkt[(size_t)b * BCAP + dst] = stage[i];
        }
    }
}

// ---------------- exclusive scan of bucket totals -> part[b] (single tiny block) ----------------
__global__ __launch_bounds__(512) void scan_partials(const int* __restrict__ bcnt,
                                                     int* __restrict__ part) {
    __shared__ int buf[2][512];
    const int t = threadIdx.x;
    const int v = (t < NB) ? min(bcnt[t * BSTRIDE], BCAP) : 0;
    buf[0][t] = v;
    __syncthreads();
    int cur = 0;
#pragma unroll
    for (int o = 1; o < 512; o <<= 1) {
        const int nv = buf[cur][t] + ((t >= o) ? buf[cur][t - o] : 0);
        buf[cur ^ 1][t] = nv;
        cur ^= 1;
        __syncthreads();
    }
    if (t < NB) part[t] = buf[cur][t] - v;  // exclusive
}

// ---------------- bucket -> CSR, single pass: bucket staged in LDS once ----------------
__global__ __launch_bounds__(256) void bucket_to_csr(const int* __restrict__ bcnt,
                                                     const int* __restrict__ part,
                                                     const int2* __restrict__ bkt,
                                                     int* __restrict__ off,
                                                     int2* __restrict__ csr_cv) {
    __shared__ int2 stage[BCAP];              // 36864 B
    __shared__ int  sA[256], sB[256], lcur[256];
    const int b = blockIdx.x;
    const int t = threadIdx.x;
    const int n = min(bcnt[b * BSTRIDE], BCAP);
    const int2* src = bkt + (size_t)b * BCAP;
    const int base = part[b];

    for (int i = t; i < n; i += 256) stage[i] = src[i];
    sA[t] = 0;
    __syncthreads();

    for (int i = t; i < n; i += 256) {
        atomicAdd(&sA[((unsigned)stage[i].x) >> 17], 1);
    }
    __syncthreads();

    int cur = 0;
    int* bufs[2] = {sA, sB};
#pragma unroll
    for (int o = 1; o < 256; o <<= 1) {
        const int* s = bufs[cur];
        int*       d = bufs[cur ^ 1];
        d[t] = s[t] + ((t >= o) ? s[t - o] : 0);
        cur ^= 1;
        __syncthreads();
    }
    const int excl = (t == 0) ? 0 : bufs[cur][t - 1];
    const int gr = (b << 8) + t;
    if (gr <= N_NODES) off[gr] = base + excl;   // covers off[N_NODES] via bucket 390
    lcur[t] = base + excl;
    __syncthreads();

    for (int i = t; i < n; i += 256) {
        const int2 e = stage[i];
        const int  rl = ((unsigned)e.x) >> 17;
        const int pos = atomicAdd(&lcur[rl], 1);
        csr_cv[pos] = make_int2(e.x & 0x1FFFF, e.y);
    }
}

// ---------------- gather: out[r] = relu(sum_j val_j * xw[col_j])  (bf16 xw) ----------------
// one wave per node; quarter-wave (16 lanes x 16 B = 256 B row) per edge,
// unrolled x4 -> 16 outstanding row loads per wave.
__global__ __launch_bounds__(256) void gather_kernel(const int* __restrict__ off,
                                                     const int2* __restrict__ csr_cv,
                                                     const ushort* __restrict__ xwb,
                                                     float* __restrict__ out) {
    const int node = blockIdx.x * 4 + (threadIdx.x >> 6);
    const int l    = threadIdx.x & 63;
    if (node >= N_NODES) return;
    const int q  = l >> 4;           // quarter 0..3
    const int lc = (l & 15) << 3;    // 8 cols per lane

    int       j   = off[node] + q;
    const int end = off[node + 1];

    float acc0[8] = {0, 0, 0, 0, 0, 0, 0, 0};
    float acc1[8] = {0, 0, 0, 0, 0, 0, 0, 0};
    float acc2[8] = {0, 0, 0, 0, 0, 0, 0, 0};
    float acc3[8] = {0, 0, 0, 0, 0, 0, 0, 0};

    for (; j + 12 < end; j += 16) {
        const int2 cva = csr_cv[j];
        const int2 cvb = csr_cv[j + 4];
        const int2 cvc = csr_cv[j + 8];
        const int2 cvd = csr_cv[j + 12];
        const short8 ma = *(const short8*)&xwb[(size_t)cva.x * D + lc];
        const short8 mb = *(const short8*)&xwb[(size_t)cvb.x * D + lc];
        const short8 mc = *(const short8*)&xwb[(size_t)cvc.x * D + lc];
        const short8 md = *(const short8*)&xwb[(size_t)cvd.x * D + lc];
        const float va = __int_as_float(cva.y);
        const float vb = __int_as_float(cvb.y);
        const float vc = __int_as_float(cvc.y);
        const float vd = __int_as_float(cvd.y);
#pragma unroll
        for (int i = 0; i < 8; ++i) {
            acc0[i] += va * bf2f((ushort)ma[i]);
            acc1[i] += vb * bf2f((ushort)mb[i]);
            acc2[i] += vc * bf2f((ushort)mc[i]);
            acc3[i] += vd * bf2f((ushort)md[i]);
        }
    }
    for (; j < end; j += 4) {
        const int2 cv = csr_cv[j];
        const short8 m = *(const short8*)&xwb[(size_t)cv.x * D + lc];
        const float v = __int_as_float(cv.y);
#pragma unroll
        for (int i = 0; i < 8; ++i) acc0[i] += v * bf2f((ushort)m[i]);
    }

#pragma unroll
    for (int i = 0; i < 8; ++i) {
        float s = (acc0[i] + acc1[i]) + (acc2[i] + acc3[i]);
        s += __shfl_down(s, 32);
        s += __shfl_down(s, 16);
        acc0[i] = fmaxf(s, 0.f);
    }

    if (q == 0) {
        floatx4 o0 = {acc0[0], acc0[1], acc0[2], acc0[3]};
        floatx4 o1 = {acc0[4], acc0[5], acc0[6], acc0[7]};
        float* o = out + (size_t)node * D + lc;
        __builtin_nontemporal_store(o0, (floatx4*)(o + 0));   // streamed; keep L2 for xwb
        __builtin_nontemporal_store(o1, (floatx4*)(o + 4));
    }
}

extern "C" void kernel_launch(void* const* d_in, const int* in_sizes, int n_in,
                              void* d_out, int out_size, void* d_ws, size_t ws_size,
                              hipStream_t stream) {
    const float* x    = (const float*)d_in[0];
    const float* w    = (const float*)d_in[1];
    const int*   erow = (const int*)d_in[2];
    const int*   ecol = (const int*)d_in[3];
    const float* eval = (const float*)d_in[4];
    float*       out  = (float*)d_out;

    // workspace layout (16 B aligned):
    char*   ws_base = (char*)d_ws;
    ushort* xwb    = (ushort*)ws_base;                   // 25,600,000 B  bf16 xw
    int*    bcnt   = (int*)(ws_base + 25600000);         //     25,024 B  (391 * 64 B)
    int*    off    = (int*)(ws_base + 25625024);         //    400,016 B  (N+1 ints)
    int*    part   = (int*)(ws_base + 26025040);         //      1,568 B
    int2*   bkt    = (int2*)(ws_base + 26026608);        // 14,413,824 B  (391 * 4608 * 8)
    int2*   csr_cv = (int2*)(ws_base + 40440432);        // 12,800,000 B
    // total ~53.2 MB

    (void)hipMemsetAsync(bcnt, 0, 25024, stream);

    gemm_and_scatter<<<NGEMM + NSCAT, 256, 0, stream>>>(x, w, xwb, erow, ecol, eval, bcnt, bkt);
    scan_partials<<<1, 512, 0, stream>>>(bcnt, part);
    bucket_to_csr<<<NB, 256, 0, stream>>>(bcnt, part, bkt, off, csr_cv);     // 391 blocks
    gather_kernel<<<(N_NODES + 3) / 4, 256, 0, stream>>>(off, csr_cv, xwb, out);
}

// Round 9
// 230.307 us; speedup vs baseline: 1.1092x; 1.1092x over previous
//
#include <hip/hip_runtime.h>

#define N_NODES 100000
#define N_EDGES 1600000
#define D 128
#define NB 512        // buckets; b = r*512/100000, ~195.3 rows, mean 3125 edges
#define BCAP 3584     // mean 3125 + 8 sigma (~56) rounded up
#define BSTRIDE 16    // bucket counter padding (64 B)
#define CHUNK 4000    // edges per scatter block; 400 blocks x 4000 = 1.6M exactly
#define NSCAT 400
#define NGEMM 1563    // ceil(100000/64)

typedef __attribute__((ext_vector_type(8))) short  short8;   // 8 bf16 (4 VGPR) MFMA A/B frag
typedef __attribute__((ext_vector_type(4))) float  floatx4;  // MFMA C/D frag

__device__ __forceinline__ ushort f2bf(float f) {   // fp32 -> bf16 RNE
    unsigned u = __float_as_uint(f);
    u += 0x7FFF + ((u >> 16) & 1);
    return (ushort)(u >> 16);
}
__device__ __forceinline__ float bf2f(ushort s) {
    return __uint_as_float((unsigned)s << 16);
}
__device__ __forceinline__ int bucket_of(int r)  { return (int)(((unsigned)r << 9) / 100000u); }
__device__ __forceinline__ int row_start(int b)  { return (b * 100000 + 511) >> 9; }

// ---------------- fused: gemm (blocks 0..NGEMM) + bucket_scatter (rest) ----------------
union SMem {
    struct {                       // scatter branch: 48192 B
        int2  stage[CHUNK];        // 32000
        int   sA[NB];              //  2048
        int   sB[NB];              //  2048
        int   lcur[NB];            //  2048
        int   gbase[NB];           //  2048
        short sbuck[CHUNK];        //  8000
    } sc;
    ushort wt[128 * 128];          // gemm branch: 32768 B
};

__global__ __launch_bounds__(256) void gemm_and_scatter(const float* __restrict__ x,
                                                        const float* __restrict__ w,
                                                        ushort* __restrict__ xwb,
                                                        const int* __restrict__ erow,
                                                        const int* __restrict__ ecol,
                                                        const float* __restrict__ eval,
                                                        int* __restrict__ bcnt,
                                                        int2* __restrict__ bkt) {
    __shared__ SMem sm;
    const int t = threadIdx.x;

    if (blockIdx.x < NGEMM) {
        // ================= GEMM: xw = bf16(x @ w) via MFMA =================
        ushort* wt = sm.wt;
        const int wv   = t >> 6;
        const int lane = t & 63;
        const int m    = lane & 15;
        const int q    = lane >> 4;

        {
            const float4* w4 = (const float4*)w;   // 4096 float4 = 128x128 fp32
            for (int i = t; i < 4096; i += 256) {
                const float4 v = w4[i];
                const int k = i >> 5;
                const int n = (i & 31) << 2;
                const int c = k >> 3, kc = k & 7;
#pragma unroll
                for (int d = 0; d < 4; ++d) {
                    const float val = (d == 0) ? v.x : (d == 1) ? v.y : (d == 2) ? v.z : v.w;
                    const int nn = n + d;
                    wt[(nn << 7) | (((c ^ (nn & 15)) & 15) << 3) | kc] = f2bf(val);
                }
            }
        }
        __syncthreads();

        const int rbase = blockIdx.x * 64 + wv * 16;
        if (rbase >= N_NODES) return;              // wave-uniform

        const float* xrow = x + (size_t)(rbase + m) * D;

        floatx4 acc[8];
#pragma unroll
        for (int tt = 0; tt < 8; ++tt) acc[tt] = (floatx4){0.f, 0.f, 0.f, 0.f};

#pragma unroll
        for (int kk = 0; kk < D; kk += 32) {
            const float4 a0 = *(const float4*)(xrow + kk + q * 8);
            const float4 a1 = *(const float4*)(xrow + kk + q * 8 + 4);
            short8 a;
            a[0] = (short)f2bf(a0.x); a[1] = (short)f2bf(a0.y);
            a[2] = (short)f2bf(a0.z); a[3] = (short)f2bf(a0.w);
            a[4] = (short)f2bf(a1.x); a[5] = (short)f2bf(a1.y);
            a[6] = (short)f2bf(a1.z); a[7] = (short)f2bf(a1.w);

#pragma unroll
            for (int tt = 0; tt < 8; ++tt) {
                const int n  = tt * 16 + m;
                const int cc = (((kk >> 3) + q) ^ m) & 15;
                const short8 b = *(const short8*)&wt[(n << 7) | (cc << 3)];
                acc[tt] = __builtin_amdgcn_mfma_f32_16x16x32_bf16(a, b, acc[tt], 0, 0, 0);
            }
        }

#pragma unroll
        for (int tt = 0; tt < 8; ++tt) {
#pragma unroll
            for (int r = 0; r < 4; ++r) {
                xwb[(size_t)(rbase + q * 4 + r) * D + tt * 16 + m] = f2bf(acc[tt][r]);
            }
        }
    } else {
        // ================= bucket_scatter: LDS counting-sort by bucket =================
        const int e0 = (blockIdx.x - NGEMM) * CHUNK;
        int*   sA    = sm.sc.sA;
        int*   sB    = sm.sc.sB;
        int*   lcur  = sm.sc.lcur;
        int*   gbase = sm.sc.gbase;
        short* sbuck = sm.sc.sbuck;
        int2*  stage = sm.sc.stage;

        sA[t] = 0; sA[t + 256] = 0;
        __syncthreads();

        // pass A: histogram by bucket
        for (int i = t; i < CHUNK; i += 256) {
            atomicAdd(&sA[bucket_of(erow[e0 + i])], 1);
        }
        __syncthreads();

        // inclusive Hillis-Steele scan over 512 slots (2/thread)
        int cur = 0;
        int* bufs[2] = {sA, sB};
#pragma unroll
        for (int o = 1; o < 512; o <<= 1) {
            const int* src = bufs[cur];
            int*       dst = bufs[cur ^ 1];
            const int i0 = t, i1 = t + 256;
            dst[i0] = src[i0] + ((i0 >= o) ? src[i0 - o] : 0);
            dst[i1] = src[i1] + ((i1 >= o) ? src[i1 - o] : 0);
            cur ^= 1;
            __syncthreads();
        }
        {
            const int* incl = bufs[cur];
            int*       excl = bufs[cur ^ 1];
            excl[t]       = (t == 0) ? 0 : incl[t - 1];
            excl[t + 256] = incl[t + 255];
        }
        __syncthreads();
        int* L = bufs[cur ^ 1];   // exclusive bases; L[511] valid, total = CHUNK

        for (int b = t; b < NB; b += 256) {
            lcur[b] = L[b];
            const int cnt = ((b == NB - 1) ? CHUNK : L[b + 1]) - L[b];
            gbase[b] = (cnt > 0) ? atomicAdd(&bcnt[b * BSTRIDE], cnt) : 0;
        }
        __syncthreads();

        // pass B: place into LDS sorted by bucket; record bucket id per slot
        for (int i = t; i < CHUNK; i += 256) {
            const int   r = erow[e0 + i];
            const int   c = ecol[e0 + i];
            const float v = eval[e0 + i];
            const int   b = bucket_of(r);
            const int  rl = r - row_start(b);          // < 196, fits in 8 bits
            const int pos = atomicAdd(&lcur[b], 1);
            stage[pos] = make_int2((rl << 17) | c, __float_as_int(v));
            sbuck[pos] = (short)b;
        }
        __syncthreads();

        // flush: consecutive threads -> consecutive addresses within each run
        for (int i = t; i < CHUNK; i += 256) {
            const int b   = sbuck[i];
            const int dst = gbase[b] + (i - L[b]);
            if (dst < BCAP) bkt[(size_t)b * BCAP + dst] = stage[i];
        }
    }
}

// ---------------- fused CSR-build + gather: one block per bucket ----------------
// CSR lives entirely in LDS; out rows of this bucket written directly. 512 blocks
// = exactly 2 per CU (LDS ~60 KB -> 2 blocks/CU) -> perfect balance.
__global__ __launch_bounds__(256) void csr_gather(const int* __restrict__ bcnt,
                                                  const int2* __restrict__ bkt,
                                                  const ushort* __restrict__ xwb,
                                                  float* __restrict__ out) {
    __shared__ int2 stage[BCAP];     // 28672 B
    __shared__ int2 lcsr[BCAP];      // 28672 B
    __shared__ int  sA[256], sB[256], lcur[256];
    const int b = blockIdx.x;
    const int t = threadIdx.x;
    const int n = min(bcnt[b * BSTRIDE], BCAP);
    const int r0    = row_start(b);
    const int nrows = row_start(b + 1) - r0;     // <= 196

    const int2* src = bkt + (size_t)b * BCAP;
    for (int i = t; i < n; i += 256) stage[i] = src[i];
    sA[t] = 0;
    __syncthreads();

    // histogram by row-local
    for (int i = t; i < n; i += 256) {
        atomicAdd(&sA[((unsigned)stage[i].x) >> 17], 1);
    }
    __syncthreads();

    // inclusive scan over 256
    int cur = 0;
    int* bufs[2] = {sA, sB};
#pragma unroll
    for (int o = 1; o < 256; o <<= 1) {
        const int* s = bufs[cur];
        int*       d = bufs[cur ^ 1];
        d[t] = s[t] + ((t >= o) ? s[t - o] : 0);
        cur ^= 1;
        __syncthreads();
    }
    lcur[t] = (t == 0) ? 0 : bufs[cur][t - 1];   // exclusive offsets
    __syncthreads();

    // place sorted-by-row into lcsr; after this, lcur[rl] = inclusive end of row rl
    for (int i = t; i < n; i += 256) {
        const int2 e = stage[i];
        const int rl = ((unsigned)e.x) >> 17;
        const int pos = atomicAdd(&lcur[rl], 1);
        lcsr[pos] = make_int2(e.x & 0x1FFFF, e.y);
    }
    __syncthreads();

    // gather: wave wv handles local rows wv, wv+4, ... ; quarter-wave covers a
    // 256 B bf16 row; clamped x4 unroll -> 4 row-loads in flight regardless of degree.
    const int wv = t >> 6;
    const int l  = t & 63;
    const int q  = l >> 4;           // quarter 0..3
    const int lc = (l & 15) << 3;    // 8 cols per lane

    for (int ln = wv; ln < nrows; ln += 4) {
        const int start = (ln == 0) ? 0 : lcur[ln - 1];
        const int end   = lcur[ln];

        float acc0[8] = {0, 0, 0, 0, 0, 0, 0, 0};
        float acc1[8] = {0, 0, 0, 0, 0, 0, 0, 0};
        float acc2[8] = {0, 0, 0, 0, 0, 0, 0, 0};
        float acc3[8] = {0, 0, 0, 0, 0, 0, 0, 0};

        for (int j0 = start + q; j0 < end; j0 += 16) {
            const int jb = j0 + 4, jc = j0 + 8, jd = j0 + 12;
            const int2 cva = lcsr[j0];
            const int2 cvb = lcsr[min(jb, end - 1)];
            const int2 cvc = lcsr[min(jc, end - 1)];
            const int2 cvd = lcsr[min(jd, end - 1)];
            const short8 ma = *(const short8*)&xwb[(size_t)cva.x * D + lc];
            const short8 mb = *(const short8*)&xwb[(size_t)cvb.x * D + lc];
            const short8 mc = *(const short8*)&xwb[(size_t)cvc.x * D + lc];
            const short8 md = *(const short8*)&xwb[(size_t)cvd.x * D + lc];
            const float va = __int_as_float(cva.y);
            const float vb = (jb < end) ? __int_as_float(cvb.y) : 0.f;
            const float vc = (jc < end) ? __int_as_float(cvc.y) : 0.f;
            const float vd = (jd < end) ? __int_as_float(cvd.y) : 0.f;
#pragma unroll
            for (int i = 0; i < 8; ++i) {
                acc0[i] += va * bf2f((ushort)ma[i]);
                acc1[i] += vb * bf2f((ushort)mb[i]);
                acc2[i] += vc * bf2f((ushort)mc[i]);
                acc3[i] += vd * bf2f((ushort)md[i]);
            }
        }

#pragma unroll
        for (int i = 0; i < 8; ++i) {
            float s = (acc0[i] + acc1[i]) + (acc2[i] + acc3[i]);
            s += __shfl_down(s, 32);
            s += __shfl_down(s, 16);
            acc0[i] = fmaxf(s, 0.f);
        }

        if (q == 0) {
            float* o = out + (size_t)(r0 + ln) * D + lc;
            *(float4*)(o + 0) = make_float4(acc0[0], acc0[1], acc0[2], acc0[3]);
            *(float4*)(o + 4) = make_float4(acc0[4], acc0[5], acc0[6], acc0[7]);
        }
    }
}

extern "C" void kernel_launch(void* const* d_in, const int* in_sizes, int n_in,
                              void* d_out, int out_size, void* d_ws, size_t ws_size,
                              hipStream_t stream) {
    const float* x    = (const float*)d_in[0];
    const float* w    = (const float*)d_in[1];
    const int*   erow = (const int*)d_in[2];
    const int*   ecol = (const int*)d_in[3];
    const float* eval = (const float*)d_in[4];
    float*       out  = (float*)d_out;

    // workspace layout (16 B aligned):
    char*   ws_base = (char*)d_ws;
    ushort* xwb  = (ushort*)ws_base;                 // 25,600,000 B  bf16 xw
    int*    bcnt = (int*)(ws_base + 25600000);       //     32,768 B  (512 * 64 B)
    int2*   bkt  = (int2*)(ws_base + 25632768);      // 14,680,064 B  (512 * 3584 * 8)
    // total ~40.3 MB

    (void)hipMemsetAsync(bcnt, 0, 32768, stream);

    gemm_and_scatter<<<NGEMM + NSCAT, 256, 0, stream>>>(x, w, xwb, erow, ecol, eval, bcnt, bkt);
    csr_gather<<<NB, 256, 0, stream>>>(bcnt, bkt, xwb, out);
}